// Round 4
// baseline (386.069 us; speedup 1.0000x reference)
//
#include <hip/hip_runtime.h>

#define BB 1024
#define TT 512
#define HH 64
#define NB 2            // batches per block
#define NTHR 256        // 4 waves
#define HPAD 96         // h row pad (f16): 192B rows -> conflict-free b128 reads

typedef _Float16 half8 __attribute__((ext_vector_type(8)));
typedef float f32x4 __attribute__((ext_vector_type(4)));

#if defined(__has_builtin)
#  if __has_builtin(__builtin_amdgcn_rcpf)
#    define FRCP(v) __builtin_amdgcn_rcpf(v)
#  endif
#endif
#ifndef FRCP
#  define FRCP(v) (1.0f / (v))
#endif

#define MFMA16(A, B, C) __builtin_amdgcn_mfma_f32_16x16x32_f16((A), (B), (C), 0, 0, 0)

__device__ __forceinline__ float fsig(float v) {
    return FRCP(1.0f + __expf(-v));
}
__device__ __forceinline__ float ftanh(float v) {
    return fmaf(2.0f, fsig(2.0f * v), -1.0f);
}

// A-fragment loader: element e = W[row][k0+e]; same (lane-group,e)->k bijection
// as the B fragment, so the contraction is exact under any HW k permutation.
__device__ __forceinline__ half8 load_frag(const float* __restrict__ W, int row, int k0) {
    const float4* p = (const float4*)(W + row * HH + k0);
    float4 u = p[0], v = p[1];
    half8 r;
    r[0] = (_Float16)u.x; r[1] = (_Float16)u.y; r[2] = (_Float16)u.z; r[3] = (_Float16)u.w;
    r[4] = (_Float16)v.x; r[5] = (_Float16)v.y; r[6] = (_Float16)v.z; r[7] = (_Float16)v.w;
    return r;
}

// Register-resident MFMA LSTM, 2-blocks/CU edition.
// NB=2, 4 waves/block, grid=512 -> two independent barrier groups per CU so
// one block's latency chain hides under the other's issue.
// Wave w owns units 16w..16w+15 via 4 row-permuted tiles d=0..3:
// within-tile row i <- W row (i&3)*64 + 16w + 4d + (i>>2), so lane (g4,col)
// reg q holds gate q of unit 16w+4d+g4 for batch col&1 (cols replicate 8x).
// Replica index col>>1 = (layer, dtile) picks the lane's task: all 64
// (g4 x batch x layer x dtile) tasks per wave are finished lane-locally.
__global__ __launch_bounds__(NTHR, 2)
void lstm_mfma3(const float* __restrict__ x,     // [B,T] (I=1)
                const float* __restrict__ Wih0,  // [256]
                const float* __restrict__ Whh0,  // [256,64]
                const float* __restrict__ bih0,  // [256]
                const float* __restrict__ bhh0,  // [256]
                const float* __restrict__ Wih1,  // [256,64]
                const float* __restrict__ Whh1,  // [256,64]
                const float* __restrict__ bih1,  // [256]
                const float* __restrict__ bhh1,  // [256]
                const float* __restrict__ Wfc,   // [64]
                const float* __restrict__ bfc,   // [1]
                float* __restrict__ out)         // [B]
{
    __shared__ float s_x[NB][TT + 1];
    __shared__ __align__(16) _Float16 s_h0b[2][NB][HPAD];   // double-buffered
    __shared__ __align__(16) _Float16 s_h1b[2][NB][HPAD];

    const int t    = threadIdx.x;
    const int lane = t & 63;
    const int w    = t >> 6;          // wave 0..3
    const int b0   = blockIdx.x * NB;

    const int arow = lane & 15;       // A/B row within tile; D col
    const int g4   = lane >> 4;       // k-group 0..3
    const int bsrc = lane & 1;        // batch (B cols replicate 8x)
    const int rep   = (lane >> 1) & 7;
    const int layer = rep & 1;
    const int dtile = rep >> 1;       // 0..3
    const int u     = 16 * w + 4 * dtile + g4;   // my unit

    // ---- one-time: A fragments (permuted rows): 24 half8 = 96 VGPR ----
    half8 a0[4][2], a1i[4][2], a1h[4][2];   // [tile][k-half]
#pragma unroll
    for (int d = 0; d < 4; ++d) {
        const int row = (arow & 3) * 64 + 16 * w + 4 * d + (arow >> 2);
#pragma unroll
        for (int kk = 0; kk < 2; ++kk) {
            const int k0 = kk * 32 + g4 * 8;
            a0[d][kk]  = load_frag(Whh0, row, k0);
            a1i[d][kk] = load_frag(Wih1, row, k0);
            a1h[d][kk] = load_frag(Whh1, row, k0);
        }
    }

    // ---- biases as MFMA C-in ----
    f32x4 cb0[4], cb1[4];
#pragma unroll
    for (int d = 0; d < 4; ++d) {
        const int uu = 16 * w + 4 * d + g4;
#pragma unroll
        for (int q = 0; q < 4; ++q) {
            const int r = q * 64 + uu;
            cb0[d][q] = bih0[r] + bhh0[r];
            cb1[d][q] = bih1[r] + bhh1[r];
        }
    }
    // x weight for my task's 4 gates (layer-1 lanes: 0)
    float xw[4];
#pragma unroll
    for (int q = 0; q < 4; ++q) {
        xw[q] = (layer == 0) ? Wih0[q * 64 + u] : 0.0f;
    }

    // ---- stage x (coalesced) ----
#pragma unroll
    for (int k = 0; k < (NB * TT) / NTHR; ++k) {
        int idx = t + NTHR * k;
        int nb  = idx >> 9;          // / TT
        int pos = idx & (TT - 1);
        s_x[nb][pos] = x[(b0 + nb) * TT + pos];
    }
    // zero both h buffers
    {
        _Float16* z0 = &s_h0b[0][0][0];
        _Float16* z1 = &s_h1b[0][0][0];
        for (int i = t; i < 2 * NB * HPAD; i += NTHR) {
            z0[i] = (_Float16)0.0f;
            z1[i] = (_Float16)0.0f;
        }
    }

    float cst = 0.0f;   // my task's cell state
    __syncthreads();

    for (int s = 0; s <= TT; ++s) {
        const int rb = s & 1;
        const int wb = rb ^ 1;
        const int xs = (s < TT) ? s : (TT - 1);
        const float xv = s_x[bsrc][xs];

        const _Float16* h0p = &s_h0b[rb][bsrc][g4 * 8];
        const _Float16* h1p = &s_h1b[rb][bsrc][g4 * 8];
        half8 bh0_0 = *(const half8*)(h0p);        // k 0..31
        half8 bh0_1 = *(const half8*)(h0p + 32);   // k 32..63
        half8 bh1_0 = *(const half8*)(h1p);
        half8 bh1_1 = *(const half8*)(h1p + 32);

        // layer-0 gates: 4 independent 2-deep chains
        f32x4 c0[4], c1[4];
#pragma unroll
        for (int d = 0; d < 4; ++d) c0[d] = cb0[d];
#pragma unroll
        for (int d = 0; d < 4; ++d) c0[d] = MFMA16(a0[d][0], bh0_0, c0[d]);
#pragma unroll
        for (int d = 0; d < 4; ++d) c0[d] = MFMA16(a0[d][1], bh0_1, c0[d]);
        // layer-1 gates: 4 independent 4-deep chains
#pragma unroll
        for (int d = 0; d < 4; ++d) c1[d] = cb1[d];
#pragma unroll
        for (int d = 0; d < 4; ++d) c1[d] = MFMA16(a1i[d][0], bh0_0, c1[d]);
#pragma unroll
        for (int d = 0; d < 4; ++d) c1[d] = MFMA16(a1i[d][1], bh0_1, c1[d]);
#pragma unroll
        for (int d = 0; d < 4; ++d) c1[d] = MFMA16(a1h[d][0], bh1_0, c1[d]);
#pragma unroll
        for (int d = 0; d < 4; ++d) c1[d] = MFMA16(a1h[d][1], bh1_1, c1[d]);

        // lane-local task select: branch-free, compile-time indices only
        const bool d1 = (dtile & 1) != 0;
        const bool d2 = (dtile & 2) != 0;
        f32x4 ta = d1 ? c0[1] : c0[0];
        f32x4 tb = d1 ? c0[3] : c0[2];
        f32x4 t0 = d2 ? tb : ta;
        f32x4 ua = d1 ? c1[1] : c1[0];
        f32x4 ub = d1 ? c1[3] : c1[2];
        f32x4 t1 = d2 ? ub : ua;
        f32x4 gv = layer ? t1 : t0;

        float gi = fmaf(xw[0], xv, gv[0]);
        float gf = fmaf(xw[1], xv, gv[1]);
        float gg = fmaf(xw[2], xv, gv[2]);
        float go = fmaf(xw[3], xv, gv[3]);

        const bool active = layer ? (s >= 1) : (s < TT);
        if (active) {
            float i_ = fsig(gi);
            float f_ = fsig(gf);
            float g_ = ftanh(gg);
            float o_ = fsig(go);
            cst = fmaf(f_, cst, i_ * g_);
            float hn = o_ * ftanh(cst);
            _Float16* dst = layer ? &s_h1b[wb][bsrc][u] : &s_h0b[wb][bsrc][u];
            *dst = (_Float16)hn;
        }
        __syncthreads();
    }

    // ---- epilogue: out[b] = h1_last . Wfc + bfc ----
    // last write (s=TT, TT even) went to buffer 1
    if (t < NB * HH) {
        const int nb = t >> 6;
        const int j  = t & 63;
        float v = (float)s_h1b[1][nb][j] * Wfc[j];
#pragma unroll
        for (int off = 32; off > 0; off >>= 1) {
            v += __shfl_down(v, off);
        }
        if (j == 0) out[b0 + nb] = v + bfc[0];
    }
}

extern "C" void kernel_launch(void* const* d_in, const int* in_sizes, int n_in,
                              void* d_out, int out_size, void* d_ws, size_t ws_size,
                              hipStream_t stream) {
    const float* x    = (const float*)d_in[0];
    const float* Wih0 = (const float*)d_in[1];
    const float* Whh0 = (const float*)d_in[2];
    const float* bih0 = (const float*)d_in[3];
    const float* bhh0 = (const float*)d_in[4];
    const float* Wih1 = (const float*)d_in[5];
    const float* Whh1 = (const float*)d_in[6];
    const float* bih1 = (const float*)d_in[7];
    const float* bhh1 = (const float*)d_in[8];
    const float* Wfc  = (const float*)d_in[9];
    const float* bfc  = (const float*)d_in[10];
    float* out = (float*)d_out;

    lstm_mfma3<<<dim3(BB / NB), dim3(NTHR), 0, stream>>>(
        x, Wih0, Whh0, bih0, bhh0, Wih1, Whh1, bih1, bhh1, Wfc, bfc, out);
}